// Round 1
// baseline (1275.989 us; speedup 1.0000x reference)
//
#include <hip/hip_runtime.h>
#include <cstdint>
#include <cstddef>

#define NEG_SLOPE 0.2f

// ---------- helpers ----------
static __device__ __forceinline__ int edge_at(const void* ei, int is32, long long pos) {
  return is32 ? ((const int*)ei)[pos] : (int)(((const long long*)ei)[pos]);
}

// ---------- init ----------
__global__ void k_init(float* deg, int* cnt, int* flag, int n) {
  int i = blockIdx.x * blockDim.x + threadIdx.x;
  if (i < n) { deg[i] = 1.0f; cnt[i] = 0; }
  if (i == 0) flag[0] = 0;
}

// detect edge_index dtype: flag=0 -> int64 (all sampled high words zero), flag=1 -> int32
__global__ void k_detect(const int* ei32, int* flag, long long n32) {
  int i = blockIdx.x * blockDim.x + threadIdx.x;
  long long idx = 2LL * i + 1;
  if (idx < 2048 && idx < n32) {
    if (ei32[idx] != 0) atomicOr(flag, 1);
  }
}

// ---------- degree + histogram ----------
__global__ void k_degcnt(const void* __restrict__ ei, const float* __restrict__ ew,
                         const int* __restrict__ flag, float* deg, int* cnt, int E) {
  int i = blockIdx.x * blockDim.x + threadIdx.x;
  if (i >= E) return;
  int is32 = *flag;
  int dst = edge_at(ei, is32, (long long)E + i);
  atomicAdd(&deg[dst], ew[i]);
  atomicAdd(&cnt[dst], 1);
}

__global__ void k_dinv(float* deg, int n) {
  int i = blockIdx.x * blockDim.x + threadIdx.x;
  if (i >= n) return;
  float d = deg[i];
  deg[i] = (d > 0.0f) ? rsqrtf(d) : 0.0f;
}

// ---------- exclusive scan (3 phases) ----------
#define SCAN_B 1024
__global__ __launch_bounds__(SCAN_B) void k_scan1(const int* __restrict__ cnt, int* incl, int* sums, int n) {
  __shared__ int sm[SCAN_B];
  int t = threadIdx.x;
  int g = blockIdx.x * SCAN_B + t;
  int v = (g < n) ? cnt[g] : 0;
  sm[t] = v;
  __syncthreads();
  for (int d = 1; d < SCAN_B; d <<= 1) {
    int a = (t >= d) ? sm[t - d] : 0;
    __syncthreads();
    sm[t] += a;
    __syncthreads();
  }
  if (g < n) incl[g] = sm[t];
  if (t == SCAN_B - 1) sums[blockIdx.x] = sm[t];
}

__global__ __launch_bounds__(128) void k_scan2(int* sums, int nb) {
  __shared__ int sm[128];
  int t = threadIdx.x;
  sm[t] = (t < nb) ? sums[t] : 0;
  __syncthreads();
  for (int d = 1; d < 128; d <<= 1) {
    int a = (t >= d) ? sm[t - d] : 0;
    __syncthreads();
    sm[t] += a;
    __syncthreads();
  }
  if (t < nb) sums[t] = (t == 0) ? 0 : sm[t - 1];
}

__global__ void k_scan3(const int* __restrict__ incl, const int* __restrict__ cnt,
                        const int* __restrict__ sums, int* row_ptr, int* cursor, int n) {
  int g = blockIdx.x * blockDim.x + threadIdx.x;
  if (g >= n) return;
  int ip = sums[g >> 10] + incl[g];
  row_ptr[g + 1] = ip;
  cursor[g] = ip - cnt[g];
  if (g == 0) row_ptr[0] = 0;
}

// ---------- CSR fill with precomputed norm ----------
__global__ void k_fill(const void* __restrict__ ei, const float* __restrict__ ew,
                       const int* __restrict__ flag, const float* __restrict__ dinv,
                       int* cursor, int* csr_src, float* csr_norm, int E) {
  int i = blockIdx.x * blockDim.x + threadIdx.x;
  if (i >= E) return;
  int is32 = *flag;
  int s = edge_at(ei, is32, i);
  int d = edge_at(ei, is32, (long long)E + i);
  float nm = dinv[s] * ew[i] * dinv[d];
  int pos = atomicAdd(&cursor[d], 1);
  csr_src[pos] = s;
  csr_norm[pos] = nm;
}

// ---------- fp32 GEMM: Y[M x FOUT] = X[M x 128] @ W[128 x FOUT] ----------
template <int FOUT>
__global__ __launch_bounds__(256) void k_gemm(const float* __restrict__ X,
                                              const float* __restrict__ W,
                                              float* __restrict__ Y, int M) {
  constexpr int CPT = FOUT / 16;  // cols per thread
  __shared__ float Xs[64][132];          // padded: banks spread across row groups
  __shared__ float Ws[128][FOUT + 4];
  int t = threadIdx.x;
  int row0 = blockIdx.x * 64;

  // stage W (128*FOUT floats)
  for (int i = t * 4; i < 128 * FOUT; i += 256 * 4) {
    int r = i / FOUT, c = i % FOUT;
    *(float4*)&Ws[r][c] = *(const float4*)&W[i];
  }
  // stage X tile (64 rows x 128)
  for (int i = t * 4; i < 64 * 128; i += 256 * 4) {
    int r = i >> 7, c = i & 127;
    int gr = row0 + r;
    float4 v;
    if (gr < M) v = *(const float4*)&X[(size_t)gr * 128 + c];
    else v = make_float4(0.f, 0.f, 0.f, 0.f);
    *(float4*)&Xs[r][c] = v;
  }
  __syncthreads();

  int rg = t >> 4;   // 0..15 row group (4 rows each)
  int cg = t & 15;   // 0..15 col group (CPT cols each)
  float acc[4][CPT];
#pragma unroll
  for (int i = 0; i < 4; ++i)
#pragma unroll
    for (int j = 0; j < CPT; ++j) acc[i][j] = 0.f;

  for (int k = 0; k < 128; ++k) {
    float xv[4];
#pragma unroll
    for (int i = 0; i < 4; ++i) xv[i] = Xs[rg * 4 + i][k];
    float wv[CPT];
#pragma unroll
    for (int j = 0; j < CPT; ++j) wv[j] = Ws[k][cg * CPT + j];
#pragma unroll
    for (int i = 0; i < 4; ++i)
#pragma unroll
      for (int j = 0; j < CPT; ++j) acc[i][j] = fmaf(xv[i], wv[j], acc[i][j]);
  }

#pragma unroll
  for (int i = 0; i < 4; ++i) {
    int gr = row0 + rg * 4 + i;
    if (gr < M) {
#pragma unroll
      for (int j = 0; j < CPT; ++j) Y[(size_t)gr * FOUT + cg * CPT + j] = acc[i][j];
    }
  }
}

// ---------- aggregation layer 1 (F=128): pull + bias + leaky relu ----------
__global__ __launch_bounds__(256) void k_agg1(const float* __restrict__ xw, const float* __restrict__ dinv,
                                              const int* __restrict__ row_ptr, const int* __restrict__ csr_src,
                                              const float* __restrict__ csr_norm, const float* __restrict__ b1,
                                              float* __restrict__ h, int n) {
  int wid = threadIdx.x >> 6;
  int lane = threadIdx.x & 63;
  int node = blockIdx.x * 4 + wid;
  if (node >= n) return;
  float di = dinv[node];
  float snm = di * di;
  float2 acc = ((const float2*)(xw + (size_t)node * 128))[lane];
  acc.x *= snm; acc.y *= snm;
  int e0 = row_ptr[node], e1 = row_ptr[node + 1];
  for (int e = e0; e < e1; ++e) {
    int s = csr_src[e];
    float nm = csr_norm[e];
    float2 v = ((const float2*)(xw + (size_t)s * 128))[lane];
    acc.x = fmaf(v.x, nm, acc.x);
    acc.y = fmaf(v.y, nm, acc.y);
  }
  float2 b = ((const float2*)b1)[lane];
  acc.x += b.x; acc.y += b.y;
  acc.x = acc.x > 0.f ? acc.x : NEG_SLOPE * acc.x;
  acc.y = acc.y > 0.f ? acc.y : NEG_SLOPE * acc.y;
  ((float2*)(h + (size_t)node * 128))[lane] = acc;
}

// ---------- aggregation layer 2 (F=64) + bias + log_softmax ----------
__global__ __launch_bounds__(256) void k_agg2(const float* __restrict__ hw, const float* __restrict__ dinv,
                                              const int* __restrict__ row_ptr, const int* __restrict__ csr_src,
                                              const float* __restrict__ csr_norm, const float* __restrict__ b2,
                                              float* __restrict__ out, int n) {
  int wid = threadIdx.x >> 6;
  int lane = threadIdx.x & 63;
  int node = blockIdx.x * 4 + wid;
  if (node >= n) return;
  float di = dinv[node];
  float acc = hw[(size_t)node * 64 + lane] * (di * di);
  int e0 = row_ptr[node], e1 = row_ptr[node + 1];
  for (int e = e0; e < e1; ++e) {
    int s = csr_src[e];
    float nm = csr_norm[e];
    acc = fmaf(hw[(size_t)s * 64 + lane], nm, acc);
  }
  acc += b2[lane];
  float m = acc;
#pragma unroll
  for (int d = 32; d >= 1; d >>= 1) m = fmaxf(m, __shfl_xor(m, d, 64));
  float sum = expf(acc - m);
#pragma unroll
  for (int d = 32; d >= 1; d >>= 1) sum += __shfl_xor(sum, d, 64);
  out[(size_t)node * 64 + lane] = acc - m - logf(sum);
}

// ---------- launcher ----------
extern "C" void kernel_launch(void* const* d_in, const int* in_sizes, int n_in,
                              void* d_out, int out_size, void* d_ws, size_t ws_size,
                              hipStream_t stream) {
  const float* x  = (const float*)d_in[0];
  const void*  ei = d_in[1];
  const float* ew = (const float*)d_in[2];
  const float* W1 = (const float*)d_in[3];
  const float* b1 = (const float*)d_in[4];
  const float* W2 = (const float*)d_in[5];
  const float* b2 = (const float*)d_in[6];
  float* out = (float*)d_out;

  const int Fh = in_sizes[4];           // 128
  const int Fo = in_sizes[6];           // 64
  const int Fi = in_sizes[3] / Fh;      // 128
  const int N  = in_sizes[0] / Fi;      // 100000
  const int E  = in_sizes[2];           // 3200000
  (void)Fo;

  char* ws = (char*)d_ws;
  size_t o = 0;
  auto alloc = [&](size_t bytes) { size_t r = o; o += (bytes + 255) & ~(size_t)255; return r; };
  float* xw   = (float*)(ws + alloc((size_t)N * 128 * 4));  // reused as hw2 after agg1
  float* h    = (float*)(ws + alloc((size_t)N * 128 * 4));
  float* deg  = (float*)(ws + alloc((size_t)N * 4));        // becomes dinv in place
  int*   cnt  = (int*)  (ws + alloc((size_t)N * 4));
  int*   incl = (int*)  (ws + alloc((size_t)N * 4));
  int*   rp   = (int*)  (ws + alloc((size_t)(N + 1) * 4));
  int*   cur  = (int*)  (ws + alloc((size_t)N * 4));
  int*   sums = (int*)  (ws + alloc(128 * 4));
  int*   flag = (int*)  (ws + alloc(4));
  int*   csrc = (int*)  (ws + alloc((size_t)E * 4));
  float* cnrm = (float*)(ws + alloc((size_t)E * 4));
  (void)ws_size;

  const int tb = 256;
  const int nbN = (N + tb - 1) / tb;
  const int nbE = (E + tb - 1) / tb;
  const int nbS = (N + SCAN_B - 1) / SCAN_B;

  hipLaunchKernelGGL(k_init,   dim3(nbN), dim3(tb), 0, stream, deg, cnt, flag, N);
  hipLaunchKernelGGL(k_detect, dim3(1), dim3(1024), 0, stream, (const int*)ei, flag, 2LL * E);
  hipLaunchKernelGGL(k_degcnt, dim3(nbE), dim3(tb), 0, stream, ei, ew, flag, deg, cnt, E);
  hipLaunchKernelGGL(k_dinv,   dim3(nbN), dim3(tb), 0, stream, deg, N);
  hipLaunchKernelGGL(k_scan1,  dim3(nbS), dim3(SCAN_B), 0, stream, cnt, incl, sums, N);
  hipLaunchKernelGGL(k_scan2,  dim3(1), dim3(128), 0, stream, sums, nbS);
  hipLaunchKernelGGL(k_scan3,  dim3(nbN), dim3(tb), 0, stream, incl, cnt, sums, rp, cur, N);
  hipLaunchKernelGGL(k_fill,   dim3(nbE), dim3(tb), 0, stream, ei, ew, flag, deg, cur, csrc, cnrm, E);

  hipLaunchKernelGGL(k_gemm<128>, dim3((N + 63) / 64), dim3(256), 0, stream, x, W1, xw, N);
  hipLaunchKernelGGL(k_agg1,      dim3((N + 3) / 4), dim3(256), 0, stream, xw, deg, rp, csrc, cnrm, b1, h, N);
  hipLaunchKernelGGL(k_gemm<64>,  dim3((N + 63) / 64), dim3(256), 0, stream, h, W2, xw, N);
  hipLaunchKernelGGL(k_agg2,      dim3((N + 3) / 4), dim3(256), 0, stream, xw, deg, rp, csrc, cnrm, b2, out, N);
}

// Round 2
// 1020.239 us; speedup vs baseline: 1.2507x; 1.2507x over previous
//
#include <hip/hip_runtime.h>
#include <cstdint>
#include <cstddef>

#define NEG_SLOPE 0.2f

// ---------- helpers ----------
static __device__ __forceinline__ int edge_at(const void* ei, int is32, long long pos) {
  return is32 ? ((const int*)ei)[pos] : (int)(((const long long*)ei)[pos]);
}

// ---------- init ----------
__global__ void k_init(float* deg, int* cnt, int* flag, int n) {
  int i = blockIdx.x * blockDim.x + threadIdx.x;
  if (i < n) { deg[i] = 1.0f; cnt[i] = 0; }
  if (i == 0) flag[0] = 0;
}

// detect edge_index dtype: flag=0 -> int64 (all sampled high words zero), flag=1 -> int32
__global__ void k_detect(const int* ei32, int* flag, long long n32) {
  int i = blockIdx.x * blockDim.x + threadIdx.x;
  long long idx = 2LL * i + 1;
  if (idx < 2048 && idx < n32) {
    if (ei32[idx] != 0) atomicOr(flag, 1);
  }
}

// ---------- degree + histogram ----------
__global__ void k_degcnt(const void* __restrict__ ei, const float* __restrict__ ew,
                         const int* __restrict__ flag, float* deg, int* cnt, int E) {
  int i = blockIdx.x * blockDim.x + threadIdx.x;
  if (i >= E) return;
  int is32 = *flag;
  int dst = edge_at(ei, is32, (long long)E + i);
  atomicAdd(&deg[dst], ew[i]);
  atomicAdd(&cnt[dst], 1);
}

__global__ void k_dinv(float* deg, int n) {
  int i = blockIdx.x * blockDim.x + threadIdx.x;
  if (i >= n) return;
  float d = deg[i];
  deg[i] = (d > 0.0f) ? rsqrtf(d) : 0.0f;
}

// ---------- exclusive scan (3 phases) ----------
#define SCAN_B 1024
__global__ __launch_bounds__(SCAN_B) void k_scan1(const int* __restrict__ cnt, int* incl, int* sums, int n) {
  __shared__ int sm[SCAN_B];
  int t = threadIdx.x;
  int g = blockIdx.x * SCAN_B + t;
  int v = (g < n) ? cnt[g] : 0;
  sm[t] = v;
  __syncthreads();
  for (int d = 1; d < SCAN_B; d <<= 1) {
    int a = (t >= d) ? sm[t - d] : 0;
    __syncthreads();
    sm[t] += a;
    __syncthreads();
  }
  if (g < n) incl[g] = sm[t];
  if (t == SCAN_B - 1) sums[blockIdx.x] = sm[t];
}

__global__ __launch_bounds__(128) void k_scan2(int* sums, int nb) {
  __shared__ int sm[128];
  int t = threadIdx.x;
  sm[t] = (t < nb) ? sums[t] : 0;
  __syncthreads();
  for (int d = 1; d < 128; d <<= 1) {
    int a = (t >= d) ? sm[t - d] : 0;
    __syncthreads();
    sm[t] += a;
    __syncthreads();
  }
  if (t < nb) sums[t] = (t == 0) ? 0 : sm[t - 1];
}

__global__ void k_scan3(const int* __restrict__ incl, const int* __restrict__ cnt,
                        const int* __restrict__ sums, int* row_ptr, int* cursor, int n) {
  int g = blockIdx.x * blockDim.x + threadIdx.x;
  if (g >= n) return;
  int ip = sums[g >> 10] + incl[g];
  row_ptr[g + 1] = ip;
  cursor[g] = ip - cnt[g];
  if (g == 0) row_ptr[0] = 0;
}

// ---------- CSR fill: packed (src, dinv[src]*w) records; dinv[dst] factored out ----------
__global__ void k_fill(const void* __restrict__ ei, const float* __restrict__ ew,
                       const int* __restrict__ flag, const float* __restrict__ dinv,
                       int* cursor, int2* pairs, int E) {
  int i = blockIdx.x * blockDim.x + threadIdx.x;
  if (i >= E) return;
  int is32 = *flag;
  int s = edge_at(ei, is32, i);
  int d = edge_at(ei, is32, (long long)E + i);
  float nm = dinv[s] * ew[i];
  int pos = atomicAdd(&cursor[d], 1);
  pairs[pos] = make_int2(s, __float_as_int(nm));
}

// ---------- fp32 GEMM: Y[M x FOUT] = X[M x 128] @ W[128 x FOUT], 128-row tile, 8xCPT regs ----------
template <int FOUT>
__global__ __launch_bounds__(256) void k_gemm(const float* __restrict__ X,
                                              const float* __restrict__ W,
                                              float* __restrict__ Y, int M) {
  constexpr int CPT = FOUT / 16;       // 8 (FOUT=128) or 4 (FOUT=64)
  constexpr int XP = 136;              // k-major X tile row pad (136 mod 32 = 8 rotates banks with k)
  constexpr int WP = FOUT + 4;
  __shared__ float Xs[128][XP];        // Xs[k][row]
  __shared__ float Ws[128][WP];        // Ws[k][col]
  int t = threadIdx.x;
  int row0 = blockIdx.x * 128;

  // stage W (128 x FOUT)
  for (int i = t * 4; i < 128 * FOUT; i += 1024) {
    int r = i / FOUT, c = i % FOUT;
    *(float4*)&Ws[r][c] = *(const float4*)&W[i];
  }
  // stage X transposed: Xs[k][r] = X[row0+r][k]
  for (int i = t; i < 128 * 32; i += 256) {
    int r = i >> 5, c = (i & 31) * 4;
    int gr = row0 + r;
    float4 v = make_float4(0.f, 0.f, 0.f, 0.f);
    if (gr < M) v = *(const float4*)&X[(size_t)gr * 128 + c];
    Xs[c + 0][r] = v.x; Xs[c + 1][r] = v.y; Xs[c + 2][r] = v.z; Xs[c + 3][r] = v.w;
  }
  __syncthreads();

  int rg = t >> 4;   // rows rg*8 .. rg*8+7
  int cg = t & 15;   // cols cg*CPT ..
  float acc[8][CPT];
#pragma unroll
  for (int i = 0; i < 8; ++i)
#pragma unroll
    for (int j = 0; j < CPT; ++j) acc[i][j] = 0.f;

#pragma unroll 2
  for (int k = 0; k < 128; ++k) {
    float xv[8], wv[CPT];
    *(float4*)&xv[0] = *(const float4*)&Xs[k][rg * 8];
    *(float4*)&xv[4] = *(const float4*)&Xs[k][rg * 8 + 4];
    *(float4*)&wv[0] = *(const float4*)&Ws[k][cg * CPT];
    if constexpr (CPT == 8) *(float4*)&wv[4] = *(const float4*)&Ws[k][cg * CPT + 4];
#pragma unroll
    for (int i = 0; i < 8; ++i)
#pragma unroll
      for (int j = 0; j < CPT; ++j) acc[i][j] = fmaf(xv[i], wv[j], acc[i][j]);
  }

#pragma unroll
  for (int i = 0; i < 8; ++i) {
    int gr = row0 + rg * 8 + i;
    if (gr < M) {
      *(float4*)&Y[(size_t)gr * FOUT + cg * CPT] = *(float4*)&acc[i][0];
      if constexpr (CPT == 8)
        *(float4*)&Y[(size_t)gr * FOUT + cg * CPT + 4] = *(float4*)&acc[i][4];
    }
  }
}

// ---------- aggregation layer 1 (F=128): pull (unroll 8) + bias + leaky relu ----------
__global__ __launch_bounds__(256) void k_agg1(const float* __restrict__ xw, const float* __restrict__ dinv,
                                              const int* __restrict__ row_ptr, const int2* __restrict__ pairs,
                                              const float* __restrict__ b1,
                                              float* __restrict__ h, int n) {
  int wid = threadIdx.x >> 6;
  int lane = threadIdx.x & 63;
  int node = blockIdx.x * 4 + wid;
  if (node >= n) return;
  float di = dinv[node];
  const float2* xw2 = (const float2*)xw;
  float2 self = xw2[(size_t)node * 64 + lane];
  float2 acc = make_float2(self.x * di, self.y * di);   // dinv[d]*xw[d]; outer di applied at end
  int e = row_ptr[node], e1 = row_ptr[node + 1];
  for (; e + 8 <= e1; e += 8) {
    int2 p[8];
#pragma unroll
    for (int j = 0; j < 8; ++j) p[j] = pairs[e + j];
    float2 v[8];
#pragma unroll
    for (int j = 0; j < 8; ++j) v[j] = xw2[(size_t)p[j].x * 64 + lane];
#pragma unroll
    for (int j = 0; j < 8; ++j) {
      float nm = __int_as_float(p[j].y);
      acc.x = fmaf(v[j].x, nm, acc.x);
      acc.y = fmaf(v[j].y, nm, acc.y);
    }
  }
  for (; e < e1; ++e) {
    int2 p = pairs[e];
    float2 v = xw2[(size_t)p.x * 64 + lane];
    float nm = __int_as_float(p.y);
    acc.x = fmaf(v.x, nm, acc.x);
    acc.y = fmaf(v.y, nm, acc.y);
  }
  float2 b = ((const float2*)b1)[lane];
  acc.x = fmaf(acc.x, di, b.x);
  acc.y = fmaf(acc.y, di, b.y);
  acc.x = acc.x > 0.f ? acc.x : NEG_SLOPE * acc.x;
  acc.y = acc.y > 0.f ? acc.y : NEG_SLOPE * acc.y;
  ((float2*)(h + (size_t)node * 128))[lane] = acc;
}

// ---------- aggregation layer 2 (F=64) + bias + log_softmax ----------
__global__ __launch_bounds__(256) void k_agg2(const float* __restrict__ hw, const float* __restrict__ dinv,
                                              const int* __restrict__ row_ptr, const int2* __restrict__ pairs,
                                              const float* __restrict__ b2,
                                              float* __restrict__ out, int n) {
  int wid = threadIdx.x >> 6;
  int lane = threadIdx.x & 63;
  int node = blockIdx.x * 4 + wid;
  if (node >= n) return;
  float di = dinv[node];
  float acc = hw[(size_t)node * 64 + lane] * di;
  int e = row_ptr[node], e1 = row_ptr[node + 1];
  for (; e + 8 <= e1; e += 8) {
    int2 p[8];
#pragma unroll
    for (int j = 0; j < 8; ++j) p[j] = pairs[e + j];
    float v[8];
#pragma unroll
    for (int j = 0; j < 8; ++j) v[j] = hw[(size_t)p[j].x * 64 + lane];
#pragma unroll
    for (int j = 0; j < 8; ++j) acc = fmaf(v[j], __int_as_float(p[j].y), acc);
  }
  for (; e < e1; ++e) {
    int2 p = pairs[e];
    acc = fmaf(hw[(size_t)p.x * 64 + lane], __int_as_float(p.y), acc);
  }
  acc = fmaf(acc, di, b2[lane]);
  float m = acc;
#pragma unroll
  for (int d = 32; d >= 1; d >>= 1) m = fmaxf(m, __shfl_xor(m, d, 64));
  float sum = expf(acc - m);
#pragma unroll
  for (int d = 32; d >= 1; d >>= 1) sum += __shfl_xor(sum, d, 64);
  out[(size_t)node * 64 + lane] = acc - m - logf(sum);
}

// ---------- launcher ----------
extern "C" void kernel_launch(void* const* d_in, const int* in_sizes, int n_in,
                              void* d_out, int out_size, void* d_ws, size_t ws_size,
                              hipStream_t stream) {
  const float* x  = (const float*)d_in[0];
  const void*  ei = d_in[1];
  const float* ew = (const float*)d_in[2];
  const float* W1 = (const float*)d_in[3];
  const float* b1 = (const float*)d_in[4];
  const float* W2 = (const float*)d_in[5];
  const float* b2 = (const float*)d_in[6];
  float* out = (float*)d_out;

  const int Fh = in_sizes[4];           // 128
  const int Fi = in_sizes[3] / Fh;      // 128
  const int N  = in_sizes[0] / Fi;      // 100000
  const int E  = in_sizes[2];           // 3200000

  char* ws = (char*)d_ws;
  size_t o = 0;
  auto alloc = [&](size_t bytes) { size_t r = o; o += (bytes + 255) & ~(size_t)255; return r; };
  float* xw   = (float*)(ws + alloc((size_t)N * 128 * 4));  // reused as hw2 after agg1
  float* h    = (float*)(ws + alloc((size_t)N * 128 * 4));
  float* deg  = (float*)(ws + alloc((size_t)N * 4));        // becomes dinv in place
  int*   cnt  = (int*)  (ws + alloc((size_t)N * 4));
  int*   incl = (int*)  (ws + alloc((size_t)N * 4));
  int*   rp   = (int*)  (ws + alloc((size_t)(N + 1) * 4));
  int*   cur  = (int*)  (ws + alloc((size_t)N * 4));
  int*   sums = (int*)  (ws + alloc(128 * 4));
  int*   flag = (int*)  (ws + alloc(4));
  int2*  prs  = (int2*) (ws + alloc((size_t)E * 8));
  (void)ws_size;

  const int tb = 256;
  const int nbN = (N + tb - 1) / tb;
  const int nbE = (E + tb - 1) / tb;
  const int nbS = (N + SCAN_B - 1) / SCAN_B;

  hipLaunchKernelGGL(k_init,   dim3(nbN), dim3(tb), 0, stream, deg, cnt, flag, N);
  hipLaunchKernelGGL(k_detect, dim3(1), dim3(1024), 0, stream, (const int*)ei, flag, 2LL * E);
  hipLaunchKernelGGL(k_degcnt, dim3(nbE), dim3(tb), 0, stream, ei, ew, flag, deg, cnt, E);
  hipLaunchKernelGGL(k_dinv,   dim3(nbN), dim3(tb), 0, stream, deg, N);
  hipLaunchKernelGGL(k_scan1,  dim3(nbS), dim3(SCAN_B), 0, stream, cnt, incl, sums, N);
  hipLaunchKernelGGL(k_scan2,  dim3(1), dim3(128), 0, stream, sums, nbS);
  hipLaunchKernelGGL(k_scan3,  dim3(nbN), dim3(tb), 0, stream, incl, cnt, sums, rp, cur, N);
  hipLaunchKernelGGL(k_fill,   dim3(nbE), dim3(tb), 0, stream, ei, ew, flag, deg, cur, prs, E);

  hipLaunchKernelGGL(k_gemm<128>, dim3((N + 127) / 128), dim3(256), 0, stream, x, W1, xw, N);
  hipLaunchKernelGGL(k_agg1,      dim3((N + 3) / 4), dim3(256), 0, stream, xw, deg, rp, prs, b1, h, N);
  hipLaunchKernelGGL(k_gemm<64>,  dim3((N + 127) / 128), dim3(256), 0, stream, h, W2, xw, N);
  hipLaunchKernelGGL(k_agg2,      dim3((N + 3) / 4), dim3(256), 0, stream, xw, deg, rp, prs, b2, out, N);
}

// Round 3
// 732.028 us; speedup vs baseline: 1.7431x; 1.3937x over previous
//
#include <hip/hip_runtime.h>
#include <cstdint>
#include <cstddef>

#define NEG_SLOPE 0.2f
#define FIXP 33554432.0f  // 2^25

// ---------- helpers ----------
static __device__ __forceinline__ int edge_at(const void* ei, int is32, long long pos) {
  return is32 ? ((const int*)ei)[pos] : (int)(((const long long*)ei)[pos]);
}

// ---------- init ----------
__global__ void k_init(unsigned long long* packed, int* flag, int n) {
  int i = blockIdx.x * blockDim.x + threadIdx.x;
  if (i < n) packed[i] = 0ULL;
  if (i == 0) flag[0] = 0;
}

// detect edge_index dtype: flag=0 -> int64, flag=1 -> int32
__global__ void k_detect(const int* ei32, int* flag, long long n32) {
  int i = blockIdx.x * blockDim.x + threadIdx.x;
  long long idx = 2LL * i + 1;
  if (idx < 2048 && idx < n32) {
    if (ei32[idx] != 0) atomicOr(flag, 1);
  }
}

// ---------- degree+count in ONE packed u64 atomic; old count = edge rank ----------
__global__ __launch_bounds__(256) void k_degcnt(const void* __restrict__ ei, const float* __restrict__ ew,
                                                const int* __restrict__ flag,
                                                unsigned long long* __restrict__ packed,
                                                int* __restrict__ rank, int E) {
  int base = blockIdx.x * blockDim.x * 4 + threadIdx.x;
  int is32 = *flag;
#pragma unroll
  for (int j = 0; j < 4; ++j) {
    int i = base + j * 256;
    if (i < E) {
      int d = edge_at(ei, is32, (long long)E + i);
      float w = ew[i];
      unsigned long long val = (1ULL << 40) | (unsigned long long)(w * FIXP);
      unsigned long long old = atomicAdd(&packed[d], val);
      rank[i] = (int)(old >> 40);
    }
  }
}

// ---------- unpack: dinv + cnt ----------
__global__ void k_dinv(const unsigned long long* __restrict__ packed,
                       float* __restrict__ dinv, int* __restrict__ cnt, int n) {
  int i = blockIdx.x * blockDim.x + threadIdx.x;
  if (i >= n) return;
  unsigned long long v = packed[i];
  int c = (int)(v >> 40);
  float wsum = (float)(v & ((1ULL << 40) - 1)) * (1.0f / FIXP);
  float deg = 1.0f + wsum;  // self-loop weight 1
  dinv[i] = rsqrtf(deg);    // deg >= 1 > 0 always
  cnt[i] = c;
}

// ---------- exclusive scan (3 phases) ----------
#define SCAN_B 1024
__global__ __launch_bounds__(SCAN_B) void k_scan1(const int* __restrict__ cnt, int* incl, int* sums, int n) {
  __shared__ int sm[SCAN_B];
  int t = threadIdx.x;
  int g = blockIdx.x * SCAN_B + t;
  int v = (g < n) ? cnt[g] : 0;
  sm[t] = v;
  __syncthreads();
  for (int d = 1; d < SCAN_B; d <<= 1) {
    int a = (t >= d) ? sm[t - d] : 0;
    __syncthreads();
    sm[t] += a;
    __syncthreads();
  }
  if (g < n) incl[g] = sm[t];
  if (t == SCAN_B - 1) sums[blockIdx.x] = sm[t];
}

__global__ __launch_bounds__(128) void k_scan2(int* sums, int nb) {
  __shared__ int sm[128];
  int t = threadIdx.x;
  sm[t] = (t < nb) ? sums[t] : 0;
  __syncthreads();
  for (int d = 1; d < 128; d <<= 1) {
    int a = (t >= d) ? sm[t - d] : 0;
    __syncthreads();
    sm[t] += a;
    __syncthreads();
  }
  if (t < nb) sums[t] = (t == 0) ? 0 : sm[t - 1];
}

__global__ void k_scan3(const int* __restrict__ incl, const int* __restrict__ sums,
                        int* row_ptr, int n) {
  int g = blockIdx.x * blockDim.x + threadIdx.x;
  if (g >= n) return;
  row_ptr[g + 1] = sums[g >> 10] + incl[g];
  if (g == 0) row_ptr[0] = 0;
}

// ---------- CSR fill, NO atomics: pos = row_ptr[d] + rank[i] ----------
__global__ __launch_bounds__(256) void k_fill(const void* __restrict__ ei, const float* __restrict__ ew,
                                              const int* __restrict__ flag, const float* __restrict__ dinv,
                                              const int* __restrict__ row_ptr, const int* __restrict__ rank,
                                              int2* __restrict__ pairs, int E) {
  int base = blockIdx.x * blockDim.x * 4 + threadIdx.x;
  int is32 = *flag;
#pragma unroll
  for (int j = 0; j < 4; ++j) {
    int i = base + j * 256;
    if (i < E) {
      int s = edge_at(ei, is32, i);
      int d = edge_at(ei, is32, (long long)E + i);
      float nm = dinv[s] * ew[i];
      int pos = row_ptr[d] + rank[i];
      pairs[pos] = make_int2(s, __float_as_int(nm));
    }
  }
}

// ---------- fp32 GEMM: Y[M x FOUT] = X[M x 128] @ W[128 x FOUT], 128-row tile ----------
template <int FOUT>
__global__ __launch_bounds__(256) void k_gemm(const float* __restrict__ X,
                                              const float* __restrict__ W,
                                              float* __restrict__ Y, int M) {
  constexpr int CPT = FOUT / 16;
  constexpr int XP = 136;
  constexpr int WP = FOUT + 4;
  __shared__ float Xs[128][XP];        // Xs[k][row]
  __shared__ float Ws[128][WP];        // Ws[k][col]
  int t = threadIdx.x;
  int row0 = blockIdx.x * 128;

  for (int i = t * 4; i < 128 * FOUT; i += 1024) {
    int r = i / FOUT, c = i % FOUT;
    *(float4*)&Ws[r][c] = *(const float4*)&W[i];
  }
  for (int i = t; i < 128 * 32; i += 256) {
    int r = i >> 5, c = (i & 31) * 4;
    int gr = row0 + r;
    float4 v = make_float4(0.f, 0.f, 0.f, 0.f);
    if (gr < M) v = *(const float4*)&X[(size_t)gr * 128 + c];
    Xs[c + 0][r] = v.x; Xs[c + 1][r] = v.y; Xs[c + 2][r] = v.z; Xs[c + 3][r] = v.w;
  }
  __syncthreads();

  int rg = t >> 4;
  int cg = t & 15;
  float acc[8][CPT];
#pragma unroll
  for (int i = 0; i < 8; ++i)
#pragma unroll
    for (int j = 0; j < CPT; ++j) acc[i][j] = 0.f;

#pragma unroll 2
  for (int k = 0; k < 128; ++k) {
    float xv[8], wv[CPT];
    *(float4*)&xv[0] = *(const float4*)&Xs[k][rg * 8];
    *(float4*)&xv[4] = *(const float4*)&Xs[k][rg * 8 + 4];
    *(float4*)&wv[0] = *(const float4*)&Ws[k][cg * CPT];
    if constexpr (CPT == 8) *(float4*)&wv[4] = *(const float4*)&Ws[k][cg * CPT + 4];
#pragma unroll
    for (int i = 0; i < 8; ++i)
#pragma unroll
      for (int j = 0; j < CPT; ++j) acc[i][j] = fmaf(xv[i], wv[j], acc[i][j]);
  }

#pragma unroll
  for (int i = 0; i < 8; ++i) {
    int gr = row0 + rg * 8 + i;
    if (gr < M) {
      *(float4*)&Y[(size_t)gr * FOUT + cg * CPT] = *(float4*)&acc[i][0];
      if constexpr (CPT == 8)
        *(float4*)&Y[(size_t)gr * FOUT + cg * CPT + 4] = *(float4*)&acc[i][4];
    }
  }
}

// ---------- aggregation layer 1 (F=128): pull (unroll 8) + bias + leaky relu ----------
__global__ __launch_bounds__(256) void k_agg1(const float* __restrict__ xw, const float* __restrict__ dinv,
                                              const int* __restrict__ row_ptr, const int2* __restrict__ pairs,
                                              const float* __restrict__ b1,
                                              float* __restrict__ h, int n) {
  int wid = threadIdx.x >> 6;
  int lane = threadIdx.x & 63;
  int node = blockIdx.x * 4 + wid;
  if (node >= n) return;
  float di = dinv[node];
  const float2* xw2 = (const float2*)xw;
  float2 self = xw2[(size_t)node * 64 + lane];
  float2 acc = make_float2(self.x * di, self.y * di);
  int e = row_ptr[node], e1 = row_ptr[node + 1];
  for (; e + 8 <= e1; e += 8) {
    int2 p[8];
#pragma unroll
    for (int j = 0; j < 8; ++j) p[j] = pairs[e + j];
    float2 v[8];
#pragma unroll
    for (int j = 0; j < 8; ++j) v[j] = xw2[(size_t)p[j].x * 64 + lane];
#pragma unroll
    for (int j = 0; j < 8; ++j) {
      float nm = __int_as_float(p[j].y);
      acc.x = fmaf(v[j].x, nm, acc.x);
      acc.y = fmaf(v[j].y, nm, acc.y);
    }
  }
  for (; e < e1; ++e) {
    int2 p = pairs[e];
    float2 v = xw2[(size_t)p.x * 64 + lane];
    float nm = __int_as_float(p.y);
    acc.x = fmaf(v.x, nm, acc.x);
    acc.y = fmaf(v.y, nm, acc.y);
  }
  float2 b = ((const float2*)b1)[lane];
  acc.x = fmaf(acc.x, di, b.x);
  acc.y = fmaf(acc.y, di, b.y);
  acc.x = acc.x > 0.f ? acc.x : NEG_SLOPE * acc.x;
  acc.y = acc.y > 0.f ? acc.y : NEG_SLOPE * acc.y;
  ((float2*)(h + (size_t)node * 128))[lane] = acc;
}

// ---------- aggregation layer 2 (F=64) + bias + log_softmax ----------
__global__ __launch_bounds__(256) void k_agg2(const float* __restrict__ hw, const float* __restrict__ dinv,
                                              const int* __restrict__ row_ptr, const int2* __restrict__ pairs,
                                              const float* __restrict__ b2,
                                              float* __restrict__ out, int n) {
  int wid = threadIdx.x >> 6;
  int lane = threadIdx.x & 63;
  int node = blockIdx.x * 4 + wid;
  if (node >= n) return;
  float di = dinv[node];
  float acc = hw[(size_t)node * 64 + lane] * di;
  int e = row_ptr[node], e1 = row_ptr[node + 1];
  for (; e + 8 <= e1; e += 8) {
    int2 p[8];
#pragma unroll
    for (int j = 0; j < 8; ++j) p[j] = pairs[e + j];
    float v[8];
#pragma unroll
    for (int j = 0; j < 8; ++j) v[j] = hw[(size_t)p[j].x * 64 + lane];
#pragma unroll
    for (int j = 0; j < 8; ++j) acc = fmaf(v[j], __int_as_float(p[j].y), acc);
  }
  for (; e < e1; ++e) {
    int2 p = pairs[e];
    acc = fmaf(hw[(size_t)p.x * 64 + lane], __int_as_float(p.y), acc);
  }
  acc = fmaf(acc, di, b2[lane]);
  float m = acc;
#pragma unroll
  for (int d = 32; d >= 1; d >>= 1) m = fmaxf(m, __shfl_xor(m, d, 64));
  float sum = expf(acc - m);
#pragma unroll
  for (int d = 32; d >= 1; d >>= 1) sum += __shfl_xor(sum, d, 64);
  out[(size_t)node * 64 + lane] = acc - m - logf(sum);
}

// ---------- launcher ----------
extern "C" void kernel_launch(void* const* d_in, const int* in_sizes, int n_in,
                              void* d_out, int out_size, void* d_ws, size_t ws_size,
                              hipStream_t stream) {
  const float* x  = (const float*)d_in[0];
  const void*  ei = d_in[1];
  const float* ew = (const float*)d_in[2];
  const float* W1 = (const float*)d_in[3];
  const float* b1 = (const float*)d_in[4];
  const float* W2 = (const float*)d_in[5];
  const float* b2 = (const float*)d_in[6];
  float* out = (float*)d_out;

  const int Fh = in_sizes[4];           // 128
  const int Fi = in_sizes[3] / Fh;      // 128
  const int N  = in_sizes[0] / Fi;      // 100000
  const int E  = in_sizes[2];           // 3200000

  char* ws = (char*)d_ws;
  size_t o = 0;
  auto alloc = [&](size_t bytes) { size_t r = o; o += (bytes + 255) & ~(size_t)255; return r; };
  float* xw   = (float*)(ws + alloc((size_t)N * 128 * 4));  // also aliased by `packed` early
  float* h    = (float*)(ws + alloc((size_t)N * 128 * 4));  // also aliased by `rank` early
  float* dinv = (float*)(ws + alloc((size_t)N * 4));
  int*   cnt  = (int*)  (ws + alloc((size_t)N * 4));
  int*   incl = (int*)  (ws + alloc((size_t)N * 4));
  int*   rp   = (int*)  (ws + alloc((size_t)(N + 1) * 4));
  int*   sums = (int*)  (ws + alloc(128 * 4));
  int*   flag = (int*)  (ws + alloc(4));
  int2*  prs  = (int2*) (ws + alloc((size_t)E * 8));
  (void)ws_size;
  // aliases: dead ranges during graph-build phase
  unsigned long long* packed = (unsigned long long*)xw;  // N*8 <= N*128*4; dead before gemm1 writes xw
  int* rank = (int*)h;                                   // E*4  <= N*128*4 (12.8MB vs 51.2MB); dead before agg1 writes h

  const int tb = 256;
  const int nbN = (N + tb - 1) / tb;
  const int nbE4 = (E + tb * 4 - 1) / (tb * 4);
  const int nbS = (N + SCAN_B - 1) / SCAN_B;

  hipLaunchKernelGGL(k_init,   dim3(nbN), dim3(tb), 0, stream, packed, flag, N);
  hipLaunchKernelGGL(k_detect, dim3(1), dim3(1024), 0, stream, (const int*)ei, flag, 2LL * E);
  hipLaunchKernelGGL(k_degcnt, dim3(nbE4), dim3(tb), 0, stream, ei, ew, flag, packed, rank, E);
  hipLaunchKernelGGL(k_dinv,   dim3(nbN), dim3(tb), 0, stream, packed, dinv, cnt, N);
  hipLaunchKernelGGL(k_scan1,  dim3(nbS), dim3(SCAN_B), 0, stream, cnt, incl, sums, N);
  hipLaunchKernelGGL(k_scan2,  dim3(1), dim3(128), 0, stream, sums, nbS);
  hipLaunchKernelGGL(k_scan3,  dim3(nbN), dim3(tb), 0, stream, incl, sums, rp, N);
  hipLaunchKernelGGL(k_fill,   dim3(nbE4), dim3(tb), 0, stream, ei, ew, flag, dinv, rp, rank, prs, E);

  hipLaunchKernelGGL(k_gemm<128>, dim3((N + 127) / 128), dim3(256), 0, stream, x, W1, xw, N);
  hipLaunchKernelGGL(k_agg1,      dim3((N + 3) / 4), dim3(256), 0, stream, xw, dinv, rp, prs, b1, h, N);
  hipLaunchKernelGGL(k_gemm<64>,  dim3((N + 127) / 128), dim3(256), 0, stream, h, W2, xw, N);
  hipLaunchKernelGGL(k_agg2,      dim3((N + 3) / 4), dim3(256), 0, stream, xw, dinv, rp, prs, b2, out, N);
}

// Round 4
// 600.556 us; speedup vs baseline: 2.1247x; 1.2189x over previous
//
#include <hip/hip_runtime.h>
#include <cstdint>
#include <cstddef>

#define NEG_SLOPE 0.2f
#define FIXP 33554432.0f  // 2^25

// ---------- bf16 helpers (RNE) ----------
static __device__ __forceinline__ float b2f(unsigned short u) {
  return __uint_as_float((unsigned)u << 16);
}
static __device__ __forceinline__ unsigned short f2b(float f) {
  unsigned u = __float_as_uint(f);
  return (unsigned short)((u + 0x7FFFu + ((u >> 16) & 1u)) >> 16);
}
static __device__ __forceinline__ ushort4 f2b4(float4 v) {
  ushort4 r; r.x = f2b(v.x); r.y = f2b(v.y); r.z = f2b(v.z); r.w = f2b(v.w); return r;
}

// ---------- helpers ----------
static __device__ __forceinline__ int edge_at(const void* ei, int is32, long long pos) {
  return is32 ? ((const int*)ei)[pos] : (int)(((const long long*)ei)[pos]);
}

// ---------- init ----------
__global__ void k_init(unsigned long long* packed, int* flag, int n) {
  int i = blockIdx.x * blockDim.x + threadIdx.x;
  if (i < n) packed[i] = 0ULL;
  if (i == 0) flag[0] = 0;
}

// detect edge_index dtype: flag=0 -> int64, flag=1 -> int32
__global__ void k_detect(const int* ei32, int* flag, long long n32) {
  int i = blockIdx.x * blockDim.x + threadIdx.x;
  long long idx = 2LL * i + 1;
  if (idx < 2048 && idx < n32) {
    if (ei32[idx] != 0) atomicOr(flag, 1);
  }
}

// ---------- degree+count in ONE packed u64 atomic; old count = edge rank ----------
__global__ __launch_bounds__(256) void k_degcnt(const void* __restrict__ ei, const float* __restrict__ ew,
                                                const int* __restrict__ flag,
                                                unsigned long long* __restrict__ packed,
                                                int* __restrict__ rank, int E) {
  int base = blockIdx.x * blockDim.x * 8 + threadIdx.x;
  int is32 = *flag;
#pragma unroll
  for (int j = 0; j < 8; ++j) {
    int i = base + j * 256;
    if (i < E) {
      int d = edge_at(ei, is32, (long long)E + i);
      float w = ew[i];
      unsigned long long val = (1ULL << 40) | (unsigned long long)(w * FIXP);
      unsigned long long old = atomicAdd(&packed[d], val);
      rank[i] = (int)(old >> 40);
    }
  }
}

// ---------- unpack: dinv + cnt ----------
__global__ void k_dinv(const unsigned long long* __restrict__ packed,
                       float* __restrict__ dinv, int* __restrict__ cnt, int n) {
  int i = blockIdx.x * blockDim.x + threadIdx.x;
  if (i >= n) return;
  unsigned long long v = packed[i];
  int c = (int)(v >> 40);
  float wsum = (float)(v & ((1ULL << 40) - 1)) * (1.0f / FIXP);
  float deg = 1.0f + wsum;  // self-loop weight 1
  dinv[i] = rsqrtf(deg);
  cnt[i] = c;
}

// ---------- exclusive scan (3 phases) ----------
#define SCAN_B 1024
__global__ __launch_bounds__(SCAN_B) void k_scan1(const int* __restrict__ cnt, int* incl, int* sums, int n) {
  __shared__ int sm[SCAN_B];
  int t = threadIdx.x;
  int g = blockIdx.x * SCAN_B + t;
  int v = (g < n) ? cnt[g] : 0;
  sm[t] = v;
  __syncthreads();
  for (int d = 1; d < SCAN_B; d <<= 1) {
    int a = (t >= d) ? sm[t - d] : 0;
    __syncthreads();
    sm[t] += a;
    __syncthreads();
  }
  if (g < n) incl[g] = sm[t];
  if (t == SCAN_B - 1) sums[blockIdx.x] = sm[t];
}

__global__ __launch_bounds__(128) void k_scan2(int* sums, int nb) {
  __shared__ int sm[128];
  int t = threadIdx.x;
  sm[t] = (t < nb) ? sums[t] : 0;
  __syncthreads();
  for (int d = 1; d < 128; d <<= 1) {
    int a = (t >= d) ? sm[t - d] : 0;
    __syncthreads();
    sm[t] += a;
    __syncthreads();
  }
  if (t < nb) sums[t] = (t == 0) ? 0 : sm[t - 1];
}

__global__ void k_scan3(const int* __restrict__ incl, const int* __restrict__ sums,
                        int* row_ptr, int n) {
  int g = blockIdx.x * blockDim.x + threadIdx.x;
  if (g >= n) return;
  row_ptr[g + 1] = sums[g >> 10] + incl[g];
  if (g == 0) row_ptr[0] = 0;
}

// ---------- CSR fill, NO atomics: pos = row_ptr[d] + rank[i] ----------
__global__ __launch_bounds__(256) void k_fill(const void* __restrict__ ei, const float* __restrict__ ew,
                                              const int* __restrict__ flag, const float* __restrict__ dinv,
                                              const int* __restrict__ row_ptr, const int* __restrict__ rank,
                                              int2* __restrict__ pairs, int E) {
  int base = blockIdx.x * blockDim.x * 8 + threadIdx.x;
  int is32 = *flag;
#pragma unroll
  for (int j = 0; j < 8; ++j) {
    int i = base + j * 256;
    if (i < E) {
      int s = edge_at(ei, is32, i);
      int d = edge_at(ei, is32, (long long)E + i);
      float nm = dinv[s] * ew[i];
      int pos = row_ptr[d] + rank[i];
      pairs[pos] = make_int2(s, __float_as_int(nm));
    }
  }
}

// ---------- GEMM: Y_bf16[M x FOUT] = X[M x 128] @ W[128 x FOUT]; X fp32 or bf16 ----------
template <int FOUT, bool XBF>
__global__ __launch_bounds__(256) void k_gemm(const void* __restrict__ Xv,
                                              const float* __restrict__ W,
                                              ushort4* __restrict__ Y, int M) {
  constexpr int CPT = FOUT / 16;
  constexpr int XP = 136;
  constexpr int WP = FOUT + 4;
  __shared__ float Xs[128][XP];        // Xs[k][row]
  __shared__ float Ws[128][WP];        // Ws[k][col]
  int t = threadIdx.x;
  int row0 = blockIdx.x * 128;

  for (int i = t * 4; i < 128 * FOUT; i += 1024) {
    int r = i / FOUT, c = i % FOUT;
    *(float4*)&Ws[r][c] = *(const float4*)&W[i];
  }
  for (int i = t; i < 128 * 32; i += 256) {
    int r = i >> 5, c = (i & 31) * 4;
    int gr = row0 + r;
    float4 v = make_float4(0.f, 0.f, 0.f, 0.f);
    if (gr < M) {
      if constexpr (XBF) {
        ushort4 u = ((const ushort4*)Xv)[(size_t)gr * 32 + (i & 31)];
        v = make_float4(b2f(u.x), b2f(u.y), b2f(u.z), b2f(u.w));
      } else {
        v = ((const float4*)Xv)[(size_t)gr * 32 + (i & 31)];
      }
    }
    Xs[c + 0][r] = v.x; Xs[c + 1][r] = v.y; Xs[c + 2][r] = v.z; Xs[c + 3][r] = v.w;
  }
  __syncthreads();

  int rg = t >> 4;
  int cg = t & 15;
  float acc[8][CPT];
#pragma unroll
  for (int i = 0; i < 8; ++i)
#pragma unroll
    for (int j = 0; j < CPT; ++j) acc[i][j] = 0.f;

#pragma unroll 2
  for (int k = 0; k < 128; ++k) {
    float xv[8], wv[CPT];
    *(float4*)&xv[0] = *(const float4*)&Xs[k][rg * 8];
    *(float4*)&xv[4] = *(const float4*)&Xs[k][rg * 8 + 4];
    *(float4*)&wv[0] = *(const float4*)&Ws[k][cg * CPT];
    if constexpr (CPT == 8) *(float4*)&wv[4] = *(const float4*)&Ws[k][cg * CPT + 4];
#pragma unroll
    for (int i = 0; i < 8; ++i)
#pragma unroll
      for (int j = 0; j < CPT; ++j) acc[i][j] = fmaf(xv[i], wv[j], acc[i][j]);
  }

#pragma unroll
  for (int i = 0; i < 8; ++i) {
    int gr = row0 + rg * 8 + i;
    if (gr < M) {
      if constexpr (CPT == 8) {
        Y[(size_t)gr * 32 + cg * 2 + 0] = f2b4(*(float4*)&acc[i][0]);
        Y[(size_t)gr * 32 + cg * 2 + 1] = f2b4(*(float4*)&acc[i][4]);
      } else {
        Y[(size_t)gr * 16 + cg] = f2b4(*(float4*)&acc[i][0]);
      }
    }
  }
}

// ---------- agg1 (F=128, bf16 rows, 2 edges/wave-batch) + bias + leaky relu ----------
__global__ __launch_bounds__(256) void k_agg1(const ushort4* __restrict__ xwb, const float* __restrict__ dinv,
                                              const int* __restrict__ rp, const int2* __restrict__ pairs,
                                              const float* __restrict__ b1,
                                              ushort4* __restrict__ hb, int n) {
  int wid = threadIdx.x >> 6;
  int lane = threadIdx.x & 63;
  int node = blockIdx.x * 4 + wid;
  if (node >= n) return;
  int half = lane >> 5;   // which edge of the pair
  int fo = lane & 31;     // ushort4 index within row (4 feats)
  float di = dinv[node];
  float4 acc = make_float4(0.f, 0.f, 0.f, 0.f);
  int e = rp[node], e1 = rp[node + 1];
  for (; e + 16 <= e1; e += 16) {
    int2 p[8];
#pragma unroll
    for (int j = 0; j < 8; ++j) p[j] = pairs[e + 2 * j + half];
    ushort4 v[8];
#pragma unroll
    for (int j = 0; j < 8; ++j) v[j] = xwb[(size_t)p[j].x * 32 + fo];
#pragma unroll
    for (int j = 0; j < 8; ++j) {
      float nm = __int_as_float(p[j].y);
      acc.x = fmaf(b2f(v[j].x), nm, acc.x);
      acc.y = fmaf(b2f(v[j].y), nm, acc.y);
      acc.z = fmaf(b2f(v[j].z), nm, acc.z);
      acc.w = fmaf(b2f(v[j].w), nm, acc.w);
    }
  }
  for (; e < e1; e += 2) {
    int ee = e + half;
    if (ee < e1) {
      int2 p = pairs[ee];
      ushort4 v = xwb[(size_t)p.x * 32 + fo];
      float nm = __int_as_float(p.y);
      acc.x = fmaf(b2f(v.x), nm, acc.x);
      acc.y = fmaf(b2f(v.y), nm, acc.y);
      acc.z = fmaf(b2f(v.z), nm, acc.z);
      acc.w = fmaf(b2f(v.w), nm, acc.w);
    }
  }
  // merge the two edge-halves
  acc.x += __shfl_xor(acc.x, 32, 64);
  acc.y += __shfl_xor(acc.y, 32, 64);
  acc.z += __shfl_xor(acc.z, 32, 64);
  acc.w += __shfl_xor(acc.w, 32, 64);
  // self term (weight dinv[node])
  ushort4 sv = xwb[(size_t)node * 32 + fo];
  acc.x = fmaf(b2f(sv.x), di, acc.x);
  acc.y = fmaf(b2f(sv.y), di, acc.y);
  acc.z = fmaf(b2f(sv.z), di, acc.z);
  acc.w = fmaf(b2f(sv.w), di, acc.w);
  float4 b = ((const float4*)b1)[fo];
  acc.x = fmaf(acc.x, di, b.x);
  acc.y = fmaf(acc.y, di, b.y);
  acc.z = fmaf(acc.z, di, b.z);
  acc.w = fmaf(acc.w, di, b.w);
  acc.x = acc.x > 0.f ? acc.x : NEG_SLOPE * acc.x;
  acc.y = acc.y > 0.f ? acc.y : NEG_SLOPE * acc.y;
  acc.z = acc.z > 0.f ? acc.z : NEG_SLOPE * acc.z;
  acc.w = acc.w > 0.f ? acc.w : NEG_SLOPE * acc.w;
  if (half == 0) hb[(size_t)node * 32 + fo] = f2b4(acc);
}

// ---------- agg2 (F=64, bf16 rows, 4 edges/wave-batch) + bias + log_softmax ----------
__global__ __launch_bounds__(256) void k_agg2(const ushort4* __restrict__ hwb, const float* __restrict__ dinv,
                                              const int* __restrict__ rp, const int2* __restrict__ pairs,
                                              const float* __restrict__ b2,
                                              float* __restrict__ out, int n) {
  int wid = threadIdx.x >> 6;
  int lane = threadIdx.x & 63;
  int node = blockIdx.x * 4 + wid;
  if (node >= n) return;
  int q = lane >> 4;      // which edge of the quad
  int fo = lane & 15;     // ushort4 index within row (4 feats)
  float di = dinv[node];
  float4 acc = make_float4(0.f, 0.f, 0.f, 0.f);
  int e = rp[node], e1 = rp[node + 1];
  for (; e + 32 <= e1; e += 32) {
    int2 p[8];
#pragma unroll
    for (int j = 0; j < 8; ++j) p[j] = pairs[e + 4 * j + q];
    ushort4 v[8];
#pragma unroll
    for (int j = 0; j < 8; ++j) v[j] = hwb[(size_t)p[j].x * 16 + fo];
#pragma unroll
    for (int j = 0; j < 8; ++j) {
      float nm = __int_as_float(p[j].y);
      acc.x = fmaf(b2f(v[j].x), nm, acc.x);
      acc.y = fmaf(b2f(v[j].y), nm, acc.y);
      acc.z = fmaf(b2f(v[j].z), nm, acc.z);
      acc.w = fmaf(b2f(v[j].w), nm, acc.w);
    }
  }
  for (; e < e1; e += 4) {
    int ee = e + q;
    if (ee < e1) {
      int2 p = pairs[ee];
      ushort4 v = hwb[(size_t)p.x * 16 + fo];
      float nm = __int_as_float(p.y);
      acc.x = fmaf(b2f(v.x), nm, acc.x);
      acc.y = fmaf(b2f(v.y), nm, acc.y);
      acc.z = fmaf(b2f(v.z), nm, acc.z);
      acc.w = fmaf(b2f(v.w), nm, acc.w);
    }
  }
  // merge the four edge-quarters
#pragma unroll
  for (int d = 32; d >= 16; d >>= 1) {
    acc.x += __shfl_xor(acc.x, d, 64);
    acc.y += __shfl_xor(acc.y, d, 64);
    acc.z += __shfl_xor(acc.z, d, 64);
    acc.w += __shfl_xor(acc.w, d, 64);
  }
  // self term
  ushort4 sv = hwb[(size_t)node * 16 + fo];
  acc.x = fmaf(b2f(sv.x), di, acc.x);
  acc.y = fmaf(b2f(sv.y), di, acc.y);
  acc.z = fmaf(b2f(sv.z), di, acc.z);
  acc.w = fmaf(b2f(sv.w), di, acc.w);
  float4 b = ((const float4*)b2)[fo];
  acc.x = fmaf(acc.x, di, b.x);
  acc.y = fmaf(acc.y, di, b.y);
  acc.z = fmaf(acc.z, di, b.z);
  acc.w = fmaf(acc.w, di, b.w);
  // log_softmax over 64 feats: per-lane max of 4, xor-reduce over 16 lanes
  float m = fmaxf(fmaxf(acc.x, acc.y), fmaxf(acc.z, acc.w));
#pragma unroll
  for (int d = 8; d >= 1; d >>= 1) m = fmaxf(m, __shfl_xor(m, d, 64));
  float s = expf(acc.x - m) + expf(acc.y - m) + expf(acc.z - m) + expf(acc.w - m);
#pragma unroll
  for (int d = 8; d >= 1; d >>= 1) s += __shfl_xor(s, d, 64);
  float lse = m + logf(s);
  if (q == 0) {
    float4 o = make_float4(acc.x - lse, acc.y - lse, acc.z - lse, acc.w - lse);
    ((float4*)out)[(size_t)node * 16 + fo] = o;
  }
}

// ---------- launcher ----------
extern "C" void kernel_launch(void* const* d_in, const int* in_sizes, int n_in,
                              void* d_out, int out_size, void* d_ws, size_t ws_size,
                              hipStream_t stream) {
  const float* x  = (const float*)d_in[0];
  const void*  ei = d_in[1];
  const float* ew = (const float*)d_in[2];
  const float* W1 = (const float*)d_in[3];
  const float* b1 = (const float*)d_in[4];
  const float* W2 = (const float*)d_in[5];
  const float* b2 = (const float*)d_in[6];
  float* out = (float*)d_out;

  const int Fh = in_sizes[4];           // 128
  const int Fi = in_sizes[3] / Fh;      // 128
  const int N  = in_sizes[0] / Fi;      // 100000
  const int E  = in_sizes[2];           // 3200000

  char* ws = (char*)d_ws;
  size_t o = 0;
  auto alloc = [&](size_t bytes) { size_t r = o; o += (bytes + 255) & ~(size_t)255; return r; };
  ushort4* xwb = (ushort4*)(ws + alloc((size_t)N * 128 * 2));  // bf16 [N][128]; aliased by `packed` early; reused as hw after agg1
  ushort4* hb  = (ushort4*)(ws + alloc((size_t)N * 128 * 2));  // bf16 [N][128]; aliased by `rank` early
  float* dinv = (float*)(ws + alloc((size_t)N * 4));
  int*   cnt  = (int*)  (ws + alloc((size_t)N * 4));
  int*   incl = (int*)  (ws + alloc((size_t)N * 4));
  int*   rp   = (int*)  (ws + alloc((size_t)(N + 1) * 4));
  int*   sums = (int*)  (ws + alloc(128 * 4));
  int*   flag = (int*)  (ws + alloc(4));
  int2*  prs  = (int2*) (ws + alloc((size_t)E * 8));
  (void)ws_size;
  unsigned long long* packed = (unsigned long long*)xwb;  // N*8 <= N*256
  int* rank = (int*)hb;                                   // E*4 = 12.8MB <= 25.6MB

  const int tb = 256;
  const int nbN = (N + tb - 1) / tb;
  const int nbE8 = (E + tb * 8 - 1) / (tb * 8);
  const int nbS = (N + SCAN_B - 1) / SCAN_B;

  hipLaunchKernelGGL(k_init,   dim3(nbN), dim3(tb), 0, stream, packed, flag, N);
  hipLaunchKernelGGL(k_detect, dim3(1), dim3(1024), 0, stream, (const int*)ei, flag, 2LL * E);
  hipLaunchKernelGGL(k_degcnt, dim3(nbE8), dim3(tb), 0, stream, ei, ew, flag, packed, rank, E);
  hipLaunchKernelGGL(k_dinv,   dim3(nbN), dim3(tb), 0, stream, packed, dinv, cnt, N);
  hipLaunchKernelGGL(k_scan1,  dim3(nbS), dim3(SCAN_B), 0, stream, cnt, incl, sums, N);
  hipLaunchKernelGGL(k_scan2,  dim3(1), dim3(128), 0, stream, sums, nbS);
  hipLaunchKernelGGL(k_scan3,  dim3(nbN), dim3(tb), 0, stream, incl, sums, rp, N);
  hipLaunchKernelGGL(k_fill,   dim3(nbE8), dim3(tb), 0, stream, ei, ew, flag, dinv, rp, rank, prs, E);

  hipLaunchKernelGGL((k_gemm<128, false>), dim3((N + 127) / 128), dim3(256), 0, stream, (const void*)x, W1, xwb, N);
  hipLaunchKernelGGL(k_agg1,               dim3((N + 3) / 4), dim3(256), 0, stream, xwb, dinv, rp, prs, b1, hb, N);
  hipLaunchKernelGGL((k_gemm<64, true>),   dim3((N + 127) / 128), dim3(256), 0, stream, (const void*)hb, W2, xwb, N);
  hipLaunchKernelGGL(k_agg2,               dim3((N + 3) / 4), dim3(256), 0, stream, xwb, dinv, rp, prs, b2, out, N);
}